// Round 10
// baseline (237.424 us; speedup 1.0000x reference)
//
#include <hip/hip_runtime.h>
#include <hip/hip_bf16.h>
#include <math.h>

#define E_EDGES 1000000
#define N_NODES 50000
#define N_C     64
#define N_REL   8
#define NBK     782         // src buckets per side: ceil(50000/64)
#define BCAP    1536        // edges per bucket cap (mean 1280, sigma 36 -> +7.1 sigma)
#define CAP2    256         // per-rel list cap within bucket (mean 160, sigma 12.6)
#define BT      256         // 4 waves per block
#define SENT    0xFFFFFFFFu

typedef __attribute__((ext_vector_type(4))) float floatx4;
typedef __attribute__((ext_vector_type(2))) float floatx2;

static __device__ __forceinline__ unsigned pk4_fp8(float a, float b, float c, float d) {
    unsigned w = 0;
    w = __builtin_amdgcn_cvt_pk_fp8_f32(a, b, w, false);
    w = __builtin_amdgcn_cvt_pk_fp8_f32(c, d, w, true);
    return w;
}

static __device__ __forceinline__ long long pack64(unsigned lo, unsigned hi) {
    uint2 u; u.x = lo; u.y = hi;
    return __builtin_bit_cast(long long, u);
}

// kappa slot permutation (verified R11/R12): Wp8 byte (q*16 + c*8 + j) of row
// holds fp8(W[row][(2c+(j>>2))*16 + 4q + (j&3)]); AS8 row byte q*16+u holds
// elem (u>>2)*16 + 4q + (u&3).
__global__ __launch_bounds__(256) void prep_kernel(
    const float* __restrict__ assign,
    const float* __restrict__ icl,
    const float* __restrict__ la,
    unsigned char* __restrict__ Wp8,
    unsigned char* __restrict__ AS8,
    unsigned* __restrict__ gcnt,
    float* __restrict__ out)
{
    int tid = blockIdx.x * blockDim.x + threadIdx.x;
    int nth = gridDim.x * blockDim.x;
    if (tid == 0) out[0] = 0.0f;

    // zero bucket counters (64B-strided: 2*NBK entries at stride 16 u32)
    for (int i = tid; i < 2 * NBK * 16; i += nth) gcnt[i] = 0u;

    for (int idx = tid; idx < N_REL * N_C * 16; idx += nth) {
        int row = idx >> 4, dq = idx & 15;
        int q = dq >> 2, c = (dq >> 1) & 1, jh = dq & 1;
        int k0 = (2 * c + jh) * 16 + 4 * q;
        float wv[4];
        #pragma unroll
        for (int b = 0; b < 4; ++b) {
            int srci = (row << 6) + k0 + b;
            float w = 1.0f / (1.0f + __expf(-icl[srci]));
            float g = 1.0f / (1.0f + __expf(-la[srci])) * 1.2f - 0.1f;
            g = fminf(fmaxf(g, 0.0f), 1.0f);
            wv[b] = w * g;
        }
        ((unsigned*)Wp8)[idx] = pk4_fp8(wv[0], wv[1], wv[2], wv[3]);
    }

    for (int n = tid; n < N_NODES; n += nth) {
        const float4* a4 = (const float4*)(assign + (size_t)n * N_C);
        unsigned w[16];
        #pragma unroll
        for (int i = 0; i < 16; ++i) {
            float4 v = a4[i];
            w[i] = pk4_fp8(v.x, v.y, v.z, v.w);
        }
        uint4* as = (uint4*)(AS8 + (size_t)n * N_C);
        #pragma unroll
        for (int q = 0; q < 4; ++q) {
            uint4 o;
            o.x = w[0 * 4 + q];
            o.y = w[1 * 4 + q];
            o.z = w[2 * 4 + q];
            o.w = w[3 * 4 + q];
            as[q] = o;
        }
    }
}

// R9: counting-scatter all 2M edges into src-buckets of 64 nodes.
// rec = dst(16b) | srclo(6b)<<16 | rel(3b)<<22. Counters 64B-padded.
__global__ __launch_bounds__(256) void scatter_kernel(
    const int* __restrict__ ei, const int* __restrict__ et,
    const int* __restrict__ nei, const int* __restrict__ net,
    unsigned* __restrict__ buckets, unsigned* __restrict__ gcnt)
{
    int tid = blockIdx.x * blockDim.x + threadIdx.x;
    int nth = gridDim.x * blockDim.x;
    for (int e = tid; e < 2 * E_EDGES; e += nth) {
        bool isneg = e >= E_EDGES;
        int idx = isneg ? e - E_EDGES : e;
        const int* Es = isneg ? nei : ei;
        const int* Et = isneg ? net : et;
        int s = __builtin_nontemporal_load(&Es[idx]);
        int d = __builtin_nontemporal_load(&Es[E_EDGES + idx]);
        int r = __builtin_nontemporal_load(&Et[idx]);
        int b = (s >> 6) + (isneg ? NBK : 0);
        unsigned pos = atomicAdd(&gcnt[b * 16], 1u);
        if (pos < BCAP)
            buckets[(size_t)b * BCAP + pos] =
                (unsigned)d | ((unsigned)(s & 63) << 16) | ((unsigned)r << 22);
    }
}

// R9 edge pass: one block per src-bucket. The bucket's 64 src rows staged in
// LDS (streamed, 4KB); W all-relations in LDS (32KB, unswizzled -- R8's
// swizzle was self-inflicted conflict); dst is the ONLY random gather left
// (64B/edge, half of R2-R8's 128B -- attacks the measured ~10B/cyc/CU gather
// clamp that made R2-R8 invariant at 52-55us). vmcnt domain = D-gathers only;
// sched_barrier(0) after each ISSUE stops the scheduler sinking loads.
__global__ __launch_bounds__(BT, 3) void edge_kernel(
    const unsigned char* __restrict__ AS8,
    const unsigned char* __restrict__ Wp8,
    const float* __restrict__ absent_bias,
    const unsigned* __restrict__ buckets,
    const unsigned* __restrict__ gcnt,
    float* __restrict__ out)
{
    __shared__ uint4 Wl[N_REL * 64 * 4];    // 32768 B
    __shared__ uint4 Sl[64 * 4];            // 4096 B
    __shared__ unsigned list[N_REL * CAP2]; // 8192 B
    __shared__ float bias_l[N_REL];
    __shared__ unsigned cnt[N_REL];
    __shared__ float red[4];

    if (threadIdx.x < N_REL) {
        cnt[threadIdx.x] = 0u;
        bias_l[threadIdx.x] = absent_bias[threadIdx.x];
    }

    // stage W (2048 uint4, coalesced)
    {
        const uint4* Wg = (const uint4*)Wp8;
        #pragma unroll
        for (int k = 0; k < 8; ++k) {
            int e = threadIdx.x + k * BT;
            Wl[e] = Wg[e];
        }
    }

    int b = blockIdx.x;
    bool isneg = b >= NBK;
    int node0 = (isneg ? b - NBK : b) << 6;
    float sign = isneg ? 1.0f : -1.0f;

    // stage the bucket's 64 src rows (row = t>>2, quad = t&3)
    {
        int row = threadIdx.x >> 2, q = threadIdx.x & 3;
        int node = node0 + row;
        node = node < N_NODES ? node : N_NODES - 1;
        Sl[threadIdx.x] = *(const uint4*)(AS8 + ((size_t)node << 6) + q * 16);
    }
    __syncthreads();

    int nb = min((int)gcnt[b * 16], BCAP);

    // bin bucket records by relation (streamed read of sorted recs)
    for (int i = threadIdx.x; i < nb; i += BT) {
        unsigned rec = buckets[(size_t)b * BCAP + i];
        int r = (rec >> 22) & 7;
        unsigned rank = atomicAdd(&cnt[r], 1u);
        if (rank < CAP2) list[r * CAP2 + rank] = rec & 0x3FFFFFu;
    }
    __syncthreads();

    // sentinel-pad each relation's list to a multiple of 16
    if (threadIdx.x < N_REL * 16) {
        int r = threadIdx.x >> 4;
        int i = threadIdx.x & 15;
        int n = min((int)cnt[r], CAP2);
        int padded = ((n + 15) >> 4) << 4;
        int slot = n + i;
        if (slot < padded) list[r * CAP2 + slot] = SENT;
    }
    __syncthreads();

    int lane = threadIdx.x & 63;
    int wid  = __builtin_amdgcn_readfirstlane(threadIdx.x >> 6);   // 0..3
    int n16  = lane & 15;
    int quad = lane >> 4;
    float loss = 0.0f;

    int G0 = __builtin_amdgcn_readfirstlane((min((int)cnt[0], CAP2) + 15) >> 4);
    int G1 = __builtin_amdgcn_readfirstlane((min((int)cnt[1], CAP2) + 15) >> 4);
    int G2 = __builtin_amdgcn_readfirstlane((min((int)cnt[2], CAP2) + 15) >> 4);
    int G3 = __builtin_amdgcn_readfirstlane((min((int)cnt[3], CAP2) + 15) >> 4);
    int G4 = __builtin_amdgcn_readfirstlane((min((int)cnt[4], CAP2) + 15) >> 4);
    int G5 = __builtin_amdgcn_readfirstlane((min((int)cnt[5], CAP2) + 15) >> 4);
    int G6 = __builtin_amdgcn_readfirstlane((min((int)cnt[6], CAP2) + 15) >> 4);
    int G7 = __builtin_amdgcn_readfirstlane((min((int)cnt[7], CAP2) + 15) >> 4);
    int go1 = G0;
    int go2 = go1 + G1;
    int go3 = go2 + G2;
    int go4 = go3 + G3;
    int go5 = go4 + G4;
    int go6 = go5 + G5;
    int go7 = go6 + G6;
    int tg  = go7 + G7;
    int tgm1 = tg - 1;

    #define LOCATE(ITEM, R, GOF)                                   \
        do {                                                       \
            R = 0; GOF = 0;                                        \
            if ((ITEM) >= go1) { R = 1; GOF = go1; }               \
            if ((ITEM) >= go2) { R = 2; GOF = go2; }               \
            if ((ITEM) >= go3) { R = 3; GOF = go3; }               \
            if ((ITEM) >= go4) { R = 4; GOF = go4; }               \
            if ((ITEM) >= go5) { R = 5; GOF = go5; }               \
            if ((ITEM) >= go6) { R = 6; GOF = go6; }               \
            if ((ITEM) >= go7) { R = 7; GOF = go7; }               \
        } while (0)

    // branchless issue: D gather (only vmem), S + W + bias from LDS
    #define ISSUE(VIT, RECV, SREG, DREG, WF0, WF1, WF2, WF3, BI)             \
        do {                                                                 \
            int vc_ = (VIT) < tgm1 ? (VIT) : tgm1;                           \
            int r_, gof_;                                                    \
            LOCATE(vc_, r_, gof_);                                           \
            unsigned recr_ = list[r_ * CAP2 + (vc_ - gof_) * 16 + n16];      \
            RECV = (VIT) < end ? recr_ : SENT;                               \
            unsigned dm_ = RECV != SENT ? (RECV & 0xFFFFu) : 0u;             \
            unsigned slo_ = RECV != SENT ? ((RECV >> 16) & 63u) : 0u;        \
            DREG = *(const uint4*)(AS8 + ((size_t)dm_ << 6) + quad * 16);    \
            SREG = Sl[slo_ * 4 + quad];                                      \
            int rb_ = r_ * 64 + n16;                                         \
            WF0 = Wl[(rb_) * 4 + quad];                                      \
            WF1 = Wl[(rb_ + 16) * 4 + quad];                                 \
            WF2 = Wl[(rb_ + 32) * 4 + quad];                                 \
            WF3 = Wl[(rb_ + 48) * 4 + quad];                                 \
            BI = bias_l[r_];                                                 \
        } while (0)

    #define COMPUTE(RECV, SS, DD, WF0, WF1, WF2, WF3, BI)                    \
        do {                                                                 \
            long long bD0 = pack64((DD).x, (DD).y);                          \
            long long bD1 = pack64((DD).z, (DD).w);                          \
            unsigned sw0 = (SS).x, sw1 = (SS).y, sw2 = (SS).z, sw3 = (SS).w; \
            float d0 = 0.0f, d1 = 0.0f;                                      \
            {                                                                \
                floatx4 p0 = zero4, p1 = zero4;                              \
                p0 = __builtin_amdgcn_mfma_f32_16x16x32_fp8_fp8(             \
                        pack64((WF0).x, (WF0).y), bD0, p0, 0, 0, 0);         \
                p1 = __builtin_amdgcn_mfma_f32_16x16x32_fp8_fp8(             \
                        pack64((WF1).x, (WF1).y), bD0, p1, 0, 0, 0);         \
                p0 = __builtin_amdgcn_mfma_f32_16x16x32_fp8_fp8(             \
                        pack64((WF0).z, (WF0).w), bD1, p0, 0, 0, 0);         \
                p1 = __builtin_amdgcn_mfma_f32_16x16x32_fp8_fp8(             \
                        pack64((WF1).z, (WF1).w), bD1, p1, 0, 0, 0);         \
                floatx2 lo0 = __builtin_amdgcn_cvt_pk_f32_fp8((int)sw0, false);\
                floatx2 hi0 = __builtin_amdgcn_cvt_pk_f32_fp8((int)sw0, true);\
                floatx2 lo1 = __builtin_amdgcn_cvt_pk_f32_fp8((int)sw1, false);\
                floatx2 hi1 = __builtin_amdgcn_cvt_pk_f32_fp8((int)sw1, true);\
                d0 = fmaf(lo0.x, p0[0], d0); d1 = fmaf(lo1.x, p1[0], d1);    \
                d0 = fmaf(lo0.y, p0[1], d0); d1 = fmaf(lo1.y, p1[1], d1);    \
                d0 = fmaf(hi0.x, p0[2], d0); d1 = fmaf(hi1.x, p1[2], d1);    \
                d0 = fmaf(hi0.y, p0[3], d0); d1 = fmaf(hi1.y, p1[3], d1);    \
            }                                                                \
            {                                                                \
                floatx4 p0 = zero4, p1 = zero4;                              \
                p0 = __builtin_amdgcn_mfma_f32_16x16x32_fp8_fp8(             \
                        pack64((WF2).x, (WF2).y), bD0, p0, 0, 0, 0);         \
                p1 = __builtin_amdgcn_mfma_f32_16x16x32_fp8_fp8(             \
                        pack64((WF3).x, (WF3).y), bD0, p1, 0, 0, 0);         \
                p0 = __builtin_amdgcn_mfma_f32_16x16x32_fp8_fp8(             \
                        pack64((WF2).z, (WF2).w), bD1, p0, 0, 0, 0);         \
                p1 = __builtin_amdgcn_mfma_f32_16x16x32_fp8_fp8(             \
                        pack64((WF3).z, (WF3).w), bD1, p1, 0, 0, 0);         \
                floatx2 lo0 = __builtin_amdgcn_cvt_pk_f32_fp8((int)sw2, false);\
                floatx2 hi0 = __builtin_amdgcn_cvt_pk_f32_fp8((int)sw2, true);\
                floatx2 lo1 = __builtin_amdgcn_cvt_pk_f32_fp8((int)sw3, false);\
                floatx2 hi1 = __builtin_amdgcn_cvt_pk_f32_fp8((int)sw3, true);\
                d0 = fmaf(lo0.x, p0[0], d0); d1 = fmaf(lo1.x, p1[0], d1);    \
                d0 = fmaf(lo0.y, p0[1], d0); d1 = fmaf(lo1.y, p1[1], d1);    \
                d0 = fmaf(hi0.x, p0[2], d0); d1 = fmaf(hi1.x, p1[2], d1);    \
                d0 = fmaf(hi0.y, p0[3], d0); d1 = fmaf(hi1.y, p1[3], d1);    \
            }                                                                \
            float dot = d0 + d1;                                             \
            dot += __shfl_xor(dot, 16);                                      \
            dot += __shfl_xor(dot, 32);                                      \
            float x = sign * (dot + (BI));                                   \
            float sp = fmaxf(x, 0.0f) + __logf(1.0f + __expf(-fabsf(x)));    \
            bool live = (quad == 0) && (RECV != SENT);                       \
            loss += live ? sp : 0.0f;                                        \
        } while (0)

    int start = (wid * tg) >> 2;
    int end   = ((wid + 1) * tg) >> 2;

    const floatx4 zero4 = {0.0f, 0.0f, 0.0f, 0.0f};

    if (start < end) {
        unsigned recA, recB, recC;
        uint4 SA, DA, SB, DB, SC, DC;
        uint4 wA0, wA1, wA2, wA3, wB0, wB1, wB2, wB3, wC0, wC1, wC2, wC3;
        float bA, bB, bC;

        int vA = start, vB = start + 1, vC = start + 2;
        ISSUE(vA, recA, SA, DA, wA0, wA1, wA2, wA3, bA);
        ISSUE(vB, recB, SB, DB, wB0, wB1, wB2, wB3, bB);
        ISSUE(vC, recC, SC, DC, wC0, wC1, wC2, wC3, bC);
        __builtin_amdgcn_sched_barrier(0);

        int n3 = (end - start + 2) / 3;
        #pragma clang loop unroll(disable)
        for (int k = 0; k < n3; ++k) {
            COMPUTE(recA, SA, DA, wA0, wA1, wA2, wA3, bA);
            vA += 3;
            ISSUE(vA, recA, SA, DA, wA0, wA1, wA2, wA3, bA);
            __builtin_amdgcn_sched_barrier(0);

            COMPUTE(recB, SB, DB, wB0, wB1, wB2, wB3, bB);
            vB += 3;
            ISSUE(vB, recB, SB, DB, wB0, wB1, wB2, wB3, bB);
            __builtin_amdgcn_sched_barrier(0);

            COMPUTE(recC, SC, DC, wC0, wC1, wC2, wC3, bC);
            vC += 3;
            ISSUE(vC, recC, SC, DC, wC0, wC1, wC2, wC3, bC);
            __builtin_amdgcn_sched_barrier(0);
        }
    }

    loss += __shfl_xor(loss, 1);
    loss += __shfl_xor(loss, 2);
    loss += __shfl_xor(loss, 4);
    loss += __shfl_xor(loss, 8);
    loss += __shfl_xor(loss, 16);
    loss += __shfl_xor(loss, 32);
    if (lane == 0) red[wid] = loss;
    __syncthreads();
    if (threadIdx.x == 0) {
        float t = red[0] + red[1] + red[2] + red[3];
        atomicAdd(out, t * (1.0f / (float)E_EDGES));
    }
}

extern "C" void kernel_launch(void* const* d_in, const int* in_sizes, int n_in,
                              void* d_out, int out_size, void* d_ws, size_t ws_size,
                              hipStream_t stream) {
    const float* assign = (const float*)d_in[0];
    const float* icl    = (const float*)d_in[1];
    const float* la     = (const float*)d_in[2];
    const float* ab     = (const float*)d_in[3];
    const int*   ei     = (const int*)d_in[4];
    const int*   et     = (const int*)d_in[5];
    const int*   nei    = (const int*)d_in[6];
    const int*   net    = (const int*)d_in[7];
    float* out = (float*)d_out;

    // workspace layout:
    //   Wp8     @ 0          (64 KB)
    //   AS8     @ 65536      (3.2 MB)
    //   buckets @ 3265536    (2*782*1536*4 = 9.61 MB)
    //   gcnt    @ 12874752   (2*782*16*4 = 100 KB, 64B-padded counters)
    // total ~12.97 MB
    char* basep = (char*)d_ws;
    unsigned char* Wp8 = (unsigned char*)basep;
    unsigned char* AS8 = (unsigned char*)(basep + 65536);
    unsigned* buckets  = (unsigned*)(basep + 3265536);
    unsigned* gcnt     = (unsigned*)(basep + 12874752);

    prep_kernel<<<256, 256, 0, stream>>>(assign, icl, la, Wp8, AS8, gcnt, out);
    scatter_kernel<<<2048, 256, 0, stream>>>(ei, et, nei, net, buckets, gcnt);
    edge_kernel<<<2 * NBK, BT, 0, stream>>>(AS8, Wp8, ab, buckets, gcnt, out);
}

// Round 13
// 126.396 us; speedup vs baseline: 1.8784x; 1.8784x over previous
//
#include <hip/hip_runtime.h>
#include <hip/hip_bf16.h>
#include <math.h>

#define E_EDGES 1000000
#define N_NODES 50000
#define N_C     64
#define N_REL   8
#define CHB     2048        // edges per block (best measured: R3)
#define CAP     384         // per-rel LDS capacity (mean 256, sigma 15 -> 8.5 sigma)
#define NBLK    489         // ceil(1e6 / 2048)
#define BT      512         // 8 waves per block
#define SENT    0xFFFFFFFFu

typedef __attribute__((ext_vector_type(4))) float floatx4;
typedef __attribute__((ext_vector_type(2))) float floatx2;

// pack 4 fp32 -> 4 fp8 e4m3 (RNE); byte j = element j
static __device__ __forceinline__ unsigned pk4_fp8(float a, float b, float c, float d) {
    unsigned w = 0;
    w = __builtin_amdgcn_cvt_pk_fp8_f32(a, b, w, false);
    w = __builtin_amdgcn_cvt_pk_fp8_f32(c, d, w, true);
    return w;
}

static __device__ __forceinline__ long long pack64(unsigned lo, unsigned hi) {
    uint2 u; u.x = lo; u.y = hi;
    return __builtin_bit_cast(long long, u);
}

// kappa slot permutation (verified R11/R12): Wp8 byte (q*16 + c*8 + j) of row
// holds fp8(W[row][(2c+(j>>2))*16 + 4q + (j&3)]); AS8 row byte q*16+u holds
// elem (u>>2)*16 + 4q + (u&3). One b128 per lane serves both the MFMA B-op
// and the src dot.
__global__ __launch_bounds__(256) void prep_kernel(
    const float* __restrict__ assign,
    const float* __restrict__ icl,
    const float* __restrict__ la,
    unsigned char* __restrict__ Wp8,
    unsigned char* __restrict__ AS8,
    float* __restrict__ out)
{
    int tid = blockIdx.x * blockDim.x + threadIdx.x;
    int nth = gridDim.x * blockDim.x;
    if (tid == 0) out[0] = 0.0f;

    // Wp8: one thread per output dword (512 rows x 16 dwords)
    for (int idx = tid; idx < N_REL * N_C * 16; idx += nth) {
        int row = idx >> 4, dq = idx & 15;
        int q = dq >> 2, c = (dq >> 1) & 1, jh = dq & 1;
        int k0 = (2 * c + jh) * 16 + 4 * q;   // bytes b=0..3 -> k = k0 + b
        float wv[4];
        #pragma unroll
        for (int b = 0; b < 4; ++b) {
            int srci = (row << 6) + k0 + b;
            float w = 1.0f / (1.0f + __expf(-icl[srci]));
            float g = 1.0f / (1.0f + __expf(-la[srci])) * 1.2f - 0.1f;
            g = fminf(fmaxf(g, 0.0f), 1.0f);
            wv[b] = w * g;
        }
        ((unsigned*)Wp8)[idx] = pk4_fp8(wv[0], wv[1], wv[2], wv[3]);
    }

    // AS8: one thread per node row; dword[q*4 + mt] = elems [16mt+4q, +4)
    for (int n = tid; n < N_NODES; n += nth) {
        const float4* a4 = (const float4*)(assign + (size_t)n * N_C);
        unsigned w[16];
        #pragma unroll
        for (int i = 0; i < 16; ++i) {
            float4 v = a4[i];
            w[i] = pk4_fp8(v.x, v.y, v.z, v.w);   // w[i] = elems 4i..4i+3
        }
        uint4* as = (uint4*)(AS8 + (size_t)n * N_C);
        #pragma unroll
        for (int q = 0; q < 4; ++q) {
            uint4 o;
            o.x = w[0 * 4 + q];
            o.y = w[1 * 4 + q];
            o.z = w[2 * 4 + q];
            o.w = w[3 * 4 + q];
            as[q] = o;
        }
    }
}

// R10: the best-measured structure (R3: flat worklist, BT=512, depth-1
// prefetch) with its one confirmed pathology removed: launch_bounds(512,5)
// -> 102-VGPR budget, no scratch spills (R3's bounds(512,8) 64-reg cap
// caused 25MB WRITE_SIZE of spill traffic). Scalarized LOCATE (readfirstlane
// -> SALU) and batched nt-load binning carried over from R5/R6.
__global__ __launch_bounds__(BT, 5) void edge_kernel(
    const unsigned char* __restrict__ AS8,
    const unsigned char* __restrict__ Wp8,
    const float* __restrict__ absent_bias,
    const int* __restrict__ ei, const int* __restrict__ et,
    const int* __restrict__ nei, const int* __restrict__ net,
    float* __restrict__ out)
{
    __shared__ unsigned list[N_REL * CAP];   // 12288 B
    __shared__ unsigned cnt[N_REL];
    __shared__ float red[8];
    if (threadIdx.x < N_REL) cnt[threadIdx.x] = 0u;
    __syncthreads();

    int blk = blockIdx.x;
    bool isneg = blk >= NBLK;
    int lb = isneg ? blk - NBLK : blk;
    const int* Es = isneg ? nei : ei;
    const int* Et = isneg ? net : et;
    float sign = isneg ? 1.0f : -1.0f;
    int base = lb * CHB;
    int elim = min(base + CHB, E_EDGES);

    // binning: batch all nt-loads up front (4-deep MLP), then atomics
    {
        int e0 = base + threadIdx.x;
        int sv[4], dv[4], rv[4];
        bool mv[4];
        #pragma unroll
        for (int k = 0; k < 4; ++k) {
            int e = e0 + k * BT;
            mv[k] = e < elim;
            int ec = mv[k] ? e : base;
            sv[k] = __builtin_nontemporal_load(&Es[ec]);
            dv[k] = __builtin_nontemporal_load(&Es[E_EDGES + ec]);
            rv[k] = __builtin_nontemporal_load(&Et[ec]);
        }
        #pragma unroll
        for (int k = 0; k < 4; ++k) {
            if (mv[k]) {
                unsigned rank = atomicAdd(&cnt[rv[k]], 1u);
                if (rank < CAP)
                    list[rv[k] * CAP + rank] = (unsigned)sv[k] | ((unsigned)dv[k] << 16);
            }
        }
    }
    __syncthreads();

    // sentinel-pad each relation's list up to a multiple of 16 entries
    if (threadIdx.x < N_REL * 16) {
        int r = threadIdx.x >> 4;
        int i = threadIdx.x & 15;
        int n = min((int)cnt[r], CAP);
        int padded = ((n + 15) >> 4) << 4;
        int slot = n + i;
        if (slot < padded) list[r * CAP + slot] = SENT;
    }
    __syncthreads();

    int lane = threadIdx.x & 63;
    int wid  = __builtin_amdgcn_readfirstlane(threadIdx.x >> 6);   // 0..7
    int n16  = lane & 15;
    int quad = lane >> 4;
    float loss = 0.0f;

    // group-offset table, scalar-resident (readfirstlane -> SGPR)
    int G0 = __builtin_amdgcn_readfirstlane((min((int)cnt[0], CAP) + 15) >> 4);
    int G1 = __builtin_amdgcn_readfirstlane((min((int)cnt[1], CAP) + 15) >> 4);
    int G2 = __builtin_amdgcn_readfirstlane((min((int)cnt[2], CAP) + 15) >> 4);
    int G3 = __builtin_amdgcn_readfirstlane((min((int)cnt[3], CAP) + 15) >> 4);
    int G4 = __builtin_amdgcn_readfirstlane((min((int)cnt[4], CAP) + 15) >> 4);
    int G5 = __builtin_amdgcn_readfirstlane((min((int)cnt[5], CAP) + 15) >> 4);
    int G6 = __builtin_amdgcn_readfirstlane((min((int)cnt[6], CAP) + 15) >> 4);
    int G7 = __builtin_amdgcn_readfirstlane((min((int)cnt[7], CAP) + 15) >> 4);
    int go1 = G0;
    int go2 = go1 + G1;
    int go3 = go2 + G2;
    int go4 = go3 + G3;
    int go5 = go4 + G4;
    int go6 = go5 + G5;
    int go7 = go6 + G6;
    int tg  = go7 + G7;

    // locate: item -> (relation r, group offset gof); all-scalar select chain
    #define LOCATE(ITEM, R, GOF)                                   \
        do {                                                       \
            R = 0; GOF = 0;                                        \
            if ((ITEM) >= go1) { R = 1; GOF = go1; }               \
            if ((ITEM) >= go2) { R = 2; GOF = go2; }               \
            if ((ITEM) >= go3) { R = 3; GOF = go3; }               \
            if ((ITEM) >= go4) { R = 4; GOF = go4; }               \
            if ((ITEM) >= go5) { R = 5; GOF = go5; }               \
            if ((ITEM) >= go6) { R = 6; GOF = go6; }               \
            if ((ITEM) >= go7) { R = 7; GOF = go7; }               \
        } while (0)

    // fetch rec + S/D gather for a flat item (R, GOF scalar)
    #define FETCH(ITEM, R, V, SREG, DREG)                                    \
        do {                                                                 \
            int gof_;                                                        \
            LOCATE(ITEM, R, gof_);                                           \
            unsigned rec_ = list[R * CAP + ((ITEM) - gof_) * 16 + n16];      \
            V = rec_ != SENT;                                                \
            unsigned sm_ = V ? (rec_ & 0xFFFFu) : 0u;                        \
            unsigned dm_ = V ? (rec_ >> 16) : 0u;                            \
            SREG = *(const uint4*)(AS8 + ((size_t)sm_ << 6) + quad * 16);    \
            DREG = *(const uint4*)(AS8 + ((size_t)dm_ << 6) + quad * 16);    \
        } while (0)

    int start = (wid * tg) >> 3;
    int end   = ((wid + 1) * tg) >> 3;

    int rC = 0;
    bool vC = false;
    uint4 SC = {0, 0, 0, 0}, DC = {0, 0, 0, 0};
    uint4 wfm[4];
    float bias = 0.0f;
    const floatx4 zero4 = {0.0f, 0.0f, 0.0f, 0.0f};

    if (start < end) {
        FETCH(start, rC, vC, SC, DC);
        #pragma unroll
        for (int mt = 0; mt < 4; ++mt)
            wfm[mt] = *(const uint4*)(Wp8 + ((rC * 64 + mt * 16 + n16) << 6) + quad * 16);
        bias = absent_bias[rC];
    }

    for (int it = start; it < end; ++it) {
        // prefetch next item (crosses relation boundaries)
        int rN = rC;
        bool vN = false;
        uint4 SN = {0, 0, 0, 0}, DN = {0, 0, 0, 0};
        if (it + 1 < end) {
            FETCH(it + 1, rN, vN, SN, DN);
        }

        // compute current item: 16 edges, W[rC] x D then dot with S
        long long bD0 = pack64(DC.x, DC.y);   // c=0 slots (first K=32)
        long long bD1 = pack64(DC.z, DC.w);   // c=1 slots
        unsigned sw[4] = {SC.x, SC.y, SC.z, SC.w};
        float d0 = 0.0f, d1 = 0.0f;
        #pragma unroll
        for (int gidx = 0; gidx < 2; ++gidx) {
            const int ma = 2 * gidx, mb = 2 * gidx + 1;
            floatx4 p0 = zero4, p1 = zero4;
            p0 = __builtin_amdgcn_mfma_f32_16x16x32_fp8_fp8(
                    pack64(wfm[ma].x, wfm[ma].y), bD0, p0, 0, 0, 0);
            p1 = __builtin_amdgcn_mfma_f32_16x16x32_fp8_fp8(
                    pack64(wfm[mb].x, wfm[mb].y), bD0, p1, 0, 0, 0);
            p0 = __builtin_amdgcn_mfma_f32_16x16x32_fp8_fp8(
                    pack64(wfm[ma].z, wfm[ma].w), bD1, p0, 0, 0, 0);
            p1 = __builtin_amdgcn_mfma_f32_16x16x32_fp8_fp8(
                    pack64(wfm[mb].z, wfm[mb].w), bD1, p1, 0, 0, 0);
            floatx2 lo0 = __builtin_amdgcn_cvt_pk_f32_fp8((int)sw[ma], false);
            floatx2 hi0 = __builtin_amdgcn_cvt_pk_f32_fp8((int)sw[ma], true);
            floatx2 lo1 = __builtin_amdgcn_cvt_pk_f32_fp8((int)sw[mb], false);
            floatx2 hi1 = __builtin_amdgcn_cvt_pk_f32_fp8((int)sw[mb], true);
            d0 = fmaf(lo0.x, p0[0], d0);
            d1 = fmaf(lo1.x, p1[0], d1);
            d0 = fmaf(lo0.y, p0[1], d0);
            d1 = fmaf(lo1.y, p1[1], d1);
            d0 = fmaf(hi0.x, p0[2], d0);
            d1 = fmaf(hi1.x, p1[2], d1);
            d0 = fmaf(hi0.y, p0[3], d0);
            d1 = fmaf(hi1.y, p1[3], d1);
        }
        float dot = d0 + d1;
        dot += __shfl_xor(dot, 16);
        dot += __shfl_xor(dot, 32);
        if (quad == 0 && vC) {
            float x = sign * (dot + bias);
            loss += fmaxf(x, 0.0f) + __logf(1.0f + __expf(-fabsf(x)));
        }

        // rotate stage; reload W only on relation change (scalar branch,
        // taken <= 7 times per wave with the sorted flat worklist)
        if (rN != rC) {
            #pragma unroll
            for (int mt = 0; mt < 4; ++mt)
                wfm[mt] = *(const uint4*)(Wp8 + ((rN * 64 + mt * 16 + n16) << 6) + quad * 16);
            bias = absent_bias[rN];
            rC = rN;
        }
        vC = vN; SC = SN; DC = DN;
    }

    loss += __shfl_xor(loss, 1);
    loss += __shfl_xor(loss, 2);
    loss += __shfl_xor(loss, 4);
    loss += __shfl_xor(loss, 8);
    loss += __shfl_xor(loss, 16);
    loss += __shfl_xor(loss, 32);
    if (lane == 0) red[wid] = loss;
    __syncthreads();
    if (threadIdx.x == 0) {
        float t = red[0] + red[1] + red[2] + red[3]
                + red[4] + red[5] + red[6] + red[7];
        atomicAdd(out, t * (1.0f / (float)E_EDGES));
    }
}

extern "C" void kernel_launch(void* const* d_in, const int* in_sizes, int n_in,
                              void* d_out, int out_size, void* d_ws, size_t ws_size,
                              hipStream_t stream) {
    const float* assign = (const float*)d_in[0];
    const float* icl    = (const float*)d_in[1];
    const float* la     = (const float*)d_in[2];
    const float* ab     = (const float*)d_in[3];
    const int*   ei     = (const int*)d_in[4];
    const int*   et     = (const int*)d_in[5];
    const int*   nei    = (const int*)d_in[6];
    const int*   net    = (const int*)d_in[7];
    float* out = (float*)d_out;

    // workspace: Wp8 32KB (pad 64KB) | AS8 3.2MB
    char* basep = (char*)d_ws;
    unsigned char* Wp8 = (unsigned char*)basep;
    unsigned char* AS8 = (unsigned char*)(basep + 65536);

    prep_kernel<<<256, 256, 0, stream>>>(assign, icl, la, Wp8, AS8, out);
    edge_kernel<<<2 * NBLK, BT, 0, stream>>>(AS8, Wp8, ab, ei, et, nei, net, out);
}